// Round 11
// baseline (1093.728 us; speedup 1.0000x reference)
//
#include <hip/hip_runtime.h>

typedef float f32x4 __attribute__((ext_vector_type(4)));
typedef __bf16 bf16x8 __attribute__((ext_vector_type(8)));
typedef unsigned short u16x8 __attribute__((ext_vector_type(8)));

#define DEVINL static __device__ __forceinline__

DEVINL unsigned short f2bf(float f) {
    unsigned int u = __builtin_bit_cast(unsigned int, f);
    u += 0x7fffu + ((u >> 16) & 1u);   // RNE
    return (unsigned short)(u >> 16);
}
DEVINL float bf2f(unsigned short u) {
    unsigned int x = ((unsigned int)u) << 16;
    return __builtin_bit_cast(float, x);
}

// async global->LDS, 16B per lane. LDS dest is wave-uniform base + lane*16.
#define GLD16(gp, lp)                                                          \
    __builtin_amdgcn_global_load_lds(                                          \
        (const __attribute__((address_space(1))) void*)(gp),                   \
        (__attribute__((address_space(3))) void*)(lp), 16, 0, 0)

// ---------------- packing kernels ----------------
__global__ void pack_cat_k(const float* __restrict__ s0, const float* __restrict__ s1,
                           unsigned short* __restrict__ dst, int nchunks) {
    int e = blockIdx.x * 256 + threadIdx.x;   // one 8-elem chunk
    if (e >= nchunks) return;
    int row = e >> 5, ch = e & 31;
    const float* src = (ch < 16) ? (s0 + (size_t)row * 128 + ch * 8)
                                 : (s1 + (size_t)row * 128 + (ch - 16) * 8);
    float4 a = *(const float4*)src;
    float4 b = *(const float4*)(src + 4);
    u16x8 o;
    o[0] = f2bf(a.x); o[1] = f2bf(a.y); o[2] = f2bf(a.z); o[3] = f2bf(a.w);
    o[4] = f2bf(b.x); o[5] = f2bf(b.y); o[6] = f2bf(b.z); o[7] = f2bf(b.w);
    *(u16x8*)(dst + (size_t)e * 8) = o;
}

__global__ void cvt_k(const float* __restrict__ s, unsigned short* __restrict__ d, int nchunks) {
    int e = blockIdx.x * 256 + threadIdx.x;
    if (e >= nchunks) return;
    float4 a = *(const float4*)(s + (size_t)e * 8);
    float4 b = *(const float4*)(s + (size_t)e * 8 + 4);
    u16x8 o;
    o[0] = f2bf(a.x); o[1] = f2bf(a.y); o[2] = f2bf(a.z); o[3] = f2bf(a.w);
    o[4] = f2bf(b.x); o[5] = f2bf(b.y); o[6] = f2bf(b.z); o[7] = f2bf(b.w);
    *(u16x8*)(d + (size_t)e * 8) = o;
}

// ---------------- 128^2 GEMM (kept for GEMM1, K=256) ----------------
template <int EPI>
__global__ void gemm_bt_k(const unsigned short* __restrict__ A,
                          const unsigned short* __restrict__ B,
                          const float* __restrict__ bias,
                          unsigned short* __restrict__ C,
                          int M, int N, int K) {
    __shared__ unsigned short As[128 * 32];
    __shared__ unsigned short Bs[128 * 32];
    const int tid  = threadIdx.x;
    const int lane = tid & 63;
    const int wv   = tid >> 6;
    const int wr   = wv >> 1, wc = wv & 1;
    const int ntn  = N >> 7;

    const int nwg = gridDim.x;
    const int xcd = blockIdx.x & 7, blk = blockIdx.x >> 3;
    const int q = nwg >> 3, rr = nwg & 7;
    const int logical = (xcd < rr ? xcd * (q + 1) : rr * (q + 1) + (xcd - rr) * q) + blk;

    const int im   = logical / ntn, in = logical % ntn;
    const size_t rowA0 = (size_t)im * 128, rowB0 = (size_t)in * 128;

    const int e0 = tid, e1 = tid + 256;
    const int ra0 = e0 >> 2, ca0 = (e0 & 3) * 8;
    const int ra1 = e1 >> 2, ca1 = (e1 & 3) * 8;

    f32x4 acc[4][4] = {};
    const int frow = lane & 15;
    const int kb   = (lane >> 4) * 8;

    for (int k0 = 0; k0 < K; k0 += 32) {
        GLD16(A + (rowA0 + ra0) * K + k0 + ca0, (char*)As + e0 * 16);
        GLD16(A + (rowA0 + ra1) * K + k0 + ca1, (char*)As + e1 * 16);
        GLD16(B + (rowB0 + ra0) * K + k0 + ca0, (char*)Bs + e0 * 16);
        GLD16(B + (rowB0 + ra1) * K + k0 + ca1, (char*)Bs + e1 * 16);
        __syncthreads();

        bf16x8 af[4], bfr[4];
#pragma unroll
        for (int m = 0; m < 4; ++m)
            af[m] = *(const bf16x8*)&As[(wr * 64 + m * 16 + frow) * 32 + kb];
#pragma unroll
        for (int n = 0; n < 4; ++n)
            bfr[n] = *(const bf16x8*)&Bs[(wc * 64 + n * 16 + frow) * 32 + kb];
#pragma unroll
        for (int m = 0; m < 4; ++m)
#pragma unroll
            for (int n = 0; n < 4; ++n)
                acc[m][n] = __builtin_amdgcn_mfma_f32_16x16x32_bf16(af[m], bfr[n], acc[m][n], 0, 0, 0);
        __syncthreads();
    }

    const int r4 = (lane >> 4) * 4;
    const int cc = lane & 15;
#pragma unroll
    for (int n = 0; n < 4; ++n) {
        const int col = (int)rowB0 + wc * 64 + n * 16 + cc;
        const float bv = (EPI == 1) ? bias[col] : 0.0f;
#pragma unroll
        for (int m = 0; m < 4; ++m) {
            const size_t row = rowA0 + wr * 64 + m * 16 + r4;
#pragma unroll
            for (int r = 0; r < 4; ++r) {
                float v = acc[m][n][r] + bv;
                if (EPI == 1) v = v / (1.0f + __expf(-v));
                C[(row + r) * (size_t)N + col] = f2bf(v);
            }
        }
    }
}

// ---------------- 256^2 quadrant-phase GEMM (T2+T3+T4+T5, deep pipe) -------
// BM=BN=256, BK=64. 8 waves (2M x 4N). Per-wave out 128x64 split across both
// M-halves and N-halves: row(m)=mh*128+wr*64+(m&3)*16+..., col(n)=nh*128+
// wc*32+(n&1)*16+... Phase (mh,nh) consumes A-half mh + B-half nh over K=64.
// LDS: smA/smB each [parity][half][16384] = 64KB -> 128KB total.
// Stage order per group t: P1:B1(t+1) P2:A1(t+1) P3:A0(t+2) P4:B0(t+2)
// -> stage->consume 5-6 phases; uniform vmcnt(8) waits for loads issued 4
// phases earlier. Swizzle: byte ^= ((row&7)<<4) both sides (G4 form).
DEVINL int swz16(int b) { return b ^ (((b >> 7) & 7) << 4); }

template <int W>
DEVINL void vmw() {
    if constexpr (W == 8) asm volatile("s_waitcnt vmcnt(8)" ::: "memory");
    else if constexpr (W == 4) asm volatile("s_waitcnt vmcnt(4)" ::: "memory");
    else if constexpr (W == 0) asm volatile("s_waitcnt vmcnt(0)" ::: "memory");
}

template <int MH, int NH, int W, typename F>
DEVINL void qphase(char* smA, char* smB, int p, f32x4 (&acc)[8][4],
                   int wr, int wc, int fr, int kg, F&& stg) {
    char* Ab = smA + p * 32768 + MH * 16384;
    char* Bb = smB + p * 32768 + NH * 16384;
    bf16x8 aF[4][2], bF[2][2];
#pragma unroll
    for (int m2 = 0; m2 < 4; ++m2)
#pragma unroll
        for (int kk = 0; kk < 2; ++kk)
            aF[m2][kk] = *(const bf16x8*)(Ab + swz16((wr * 64 + m2 * 16 + fr) * 128 + kk * 64 + kg));
#pragma unroll
    for (int n2 = 0; n2 < 2; ++n2)
#pragma unroll
        for (int kk = 0; kk < 2; ++kk)
            bF[n2][kk] = *(const bf16x8*)(Bb + swz16((wc * 32 + n2 * 16 + fr) * 128 + kk * 64 + kg));
    stg();
    vmw<W>();
    __builtin_amdgcn_s_barrier();
    __builtin_amdgcn_s_setprio(1);
#pragma unroll
    for (int kk = 0; kk < 2; ++kk)
#pragma unroll
        for (int m2 = 0; m2 < 4; ++m2)
#pragma unroll
            for (int n2 = 0; n2 < 2; ++n2)
                acc[MH * 4 + m2][NH * 2 + n2] = __builtin_amdgcn_mfma_f32_16x16x32_bf16(
                    aF[m2][kk], bF[n2][kk], acc[MH * 4 + m2][NH * 2 + n2], 0, 0, 0);
    __builtin_amdgcn_s_setprio(0);
    __builtin_amdgcn_s_barrier();
}

template <int EPI>
__launch_bounds__(512, 1)
__global__ void gemm256_k(const unsigned short* __restrict__ A,
                          const unsigned short* __restrict__ Bm,
                          const float* __restrict__ bias,
                          unsigned short* __restrict__ C,
                          const float* __restrict__ wns,
                          float* __restrict__ sc,
                          float* __restrict__ pl,
                          int M, int N, int K) {
    extern __shared__ __align__(16) char sm[];
    char* smA = sm;            // [parity][half][16384]
    char* smB = sm + 65536;
    const int tid  = threadIdx.x;
    const int lane = tid & 63, w = tid >> 6;
    const int wr = w >> 2, wc = w & 3;       // 2 x 4 waves
    const int fr = lane & 15;
    const int kg = (lane >> 4) * 16;         // 16B k-group within 64B window
    const int ntn = N >> 8;

    const int nwg = gridDim.x;
    const int xcd = blockIdx.x & 7, blk = blockIdx.x >> 3;
    const int q = nwg >> 3, rr = nwg & 7;
    const int logical = (xcd < rr ? xcd * (q + 1) : rr * (q + 1) + (xcd - rr) * q) + blk;
    const int im = logical / ntn, in = logical % ntn;
    const size_t rowA0 = (size_t)im * 256, colB0 = (size_t)in * 256;
    const int NT = K >> 6;                   // 64-wide K-tiles (even, >=2)

    f32x4 acc[8][4] = {};

    // stage one 16KB half-tile (128 rows x 64 cols). LDS linear; source
    // column-chunk swizzled with the involution of the read swizzle.
    auto stageA = [&](int tile, int half, int par) {
#pragma unroll
        for (int j = 0; j < 2; ++j) {
            const int c = tid + j * 512;
            const int gc = (c & 7) ^ ((c >> 3) & 7);
            GLD16(A + (rowA0 + half * 128 + (c >> 3)) * K + tile * 64 + gc * 8,
                  smA + par * 32768 + half * 16384 + c * 16);
        }
    };
    auto stageB = [&](int tile, int half, int par) {
#pragma unroll
        for (int j = 0; j < 2; ++j) {
            const int c = tid + j * 512;
            const int gc = (c & 7) ^ ((c >> 3) & 7);
            GLD16(Bm + (colB0 + half * 128 + (c >> 3)) * K + tile * 64 + gc * 8,
                  smB + par * 32768 + half * 16384 + c * 16);
        }
    };
    auto nop = [] {};

    // prologue: 6 half-tiles (12 loads); wait for tile0 A0,B0.
    stageA(0, 0, 0); stageB(0, 0, 0);
    stageB(0, 1, 0); stageA(0, 1, 0);
    stageA(1, 0, 1); stageB(1, 0, 1);
    vmw<8>();
    __builtin_amdgcn_s_barrier();

    // steady groups: invariant 8 loads outstanding entering each group.
    for (int t = 0; t + 2 < NT; ++t) {
        const int p = t & 1;
        qphase<0, 0, 8>(smA, smB, p, acc, wr, wc, fr, kg, [&] { stageB(t + 1, 1, p ^ 1); });
        qphase<0, 1, 8>(smA, smB, p, acc, wr, wc, fr, kg, [&] { stageA(t + 1, 1, p ^ 1); });
        qphase<1, 0, 8>(smA, smB, p, acc, wr, wc, fr, kg, [&] { stageA(t + 2, 0, p); });
        qphase<1, 1, 8>(smA, smB, p, acc, wr, wc, fr, kg, [&] { stageB(t + 2, 0, p); });
    }
    // group NT-2: stage only t+1 halves; tighten waits for the tail.
    {
        const int t = NT - 2, p = t & 1;
        qphase<0, 0, 8>(smA, smB, p, acc, wr, wc, fr, kg, [&] { stageB(t + 1, 1, p ^ 1); });
        qphase<0, 1, 8>(smA, smB, p, acc, wr, wc, fr, kg, [&] { stageA(t + 1, 1, p ^ 1); });
        qphase<1, 0, 4>(smA, smB, p, acc, wr, wc, fr, kg, nop);
        qphase<1, 1, 0>(smA, smB, p, acc, wr, wc, fr, kg, nop);
    }
    // group NT-1: everything already landed (vmcnt==0).
    {
        const int p = (NT - 1) & 1;
        qphase<0, 0, -1>(smA, smB, p, acc, wr, wc, fr, kg, nop);
        qphase<0, 1, -1>(smA, smB, p, acc, wr, wc, fr, kg, nop);
        qphase<1, 0, -1>(smA, smB, p, acc, wr, wc, fr, kg, nop);
        qphase<1, 1, -1>(smA, smB, p, acc, wr, wc, fr, kg, nop);
    }

    // epilogue. frag: col = lane&15, row = (lane>>4)*4 + reg
    const int r4 = (lane >> 4) * 4;
    const int cc = lane & 15;
    // row(m) = mh*128 + wr*64 + (m&3)*16 + r4 + r ; col(n) = nh*128 + wc*32 + (n&1)*16 + cc

    if (EPI == 2) {
#pragma unroll
        for (int n = 0; n < 4; ++n) {
            const float bv = bias[(int)colB0 + (n >> 1) * 128 + wc * 32 + (n & 1) * 16 + cc];
#pragma unroll
            for (int m = 0; m < 8; ++m)
#pragma unroll
                for (int r = 0; r < 4; ++r) {
                    float v = acc[m][n][r] + bv;
                    acc[m][n][r] = v / (1.0f + __expf(-v));
                }
        }
        // node scores: per-(m,r) row partial over this wave's 64 cols
#pragma unroll
        for (int m = 0; m < 8; ++m)
#pragma unroll
            for (int r = 0; r < 4; ++r) {
                float s = 0.f;
#pragma unroll
                for (int n = 0; n < 4; ++n)
                    s += acc[m][n][r] * wns[(int)colB0 + (n >> 1) * 128 + wc * 32 + (n & 1) * 16 + cc];
#pragma unroll
                for (int o = 1; o < 16; o <<= 1) s += __shfl_xor(s, o);
                if (cc == 0)
                    atomicAdd(&sc[rowA0 + (m >> 2) * 128 + wr * 64 + (m & 3) * 16 + r4 + r], s);
            }
        // pool: per-n column partial over this wave's 128 rows
        const int seg = (int)(rowA0 >> 11);
#pragma unroll
        for (int n = 0; n < 4; ++n) {
            float p2 = 0.f;
#pragma unroll
            for (int m = 0; m < 8; ++m)
#pragma unroll
                for (int r = 0; r < 4; ++r) p2 += acc[m][n][r];
            p2 += __shfl_xor(p2, 16);
            p2 += __shfl_xor(p2, 32);
            if ((lane >> 4) == 0)
                atomicAdd(&pl[seg * 1024 + (int)colB0 + (n >> 1) * 128 + wc * 32 + (n & 1) * 16 + cc],
                          p2 * (1.0f / 2048.0f));
        }
        return;
    }

#pragma unroll
    for (int n = 0; n < 4; ++n) {
        const int col = (int)colB0 + (n >> 1) * 128 + wc * 32 + (n & 1) * 16 + cc;
        const float bv = bias[col];
#pragma unroll
        for (int m = 0; m < 8; ++m) {
            const size_t row = rowA0 + (m >> 2) * 128 + wr * 64 + (m & 3) * 16 + r4;
#pragma unroll
            for (int r = 0; r < 4; ++r) {
                float v = acc[m][n][r] + bv;
                v = v / (1.0f + __expf(-v));   // swish
                C[(row + r) * (size_t)N + col] = f2bf(v);
            }
        }
    }
}

// ---------------- stop head: log_softmax(pool @ W_stop^T) ----------------
__global__ void stop_k(const float* __restrict__ pool, const float* __restrict__ Wstop,
                       float* __restrict__ stp, float* __restrict__ out) {
    const int b = blockIdx.x, t = threadIdx.x;
    float a0 = 0.f, a1 = 0.f;
#pragma unroll
    for (int j = 0; j < 4; ++j) {
        const int hcol = t + j * 256;
        const float pv = pool[b * 1024 + hcol];
        a0 += pv * Wstop[hcol];
        a1 += pv * Wstop[1024 + hcol];
    }
    const int lane = t & 63, wv = t >> 6;
#pragma unroll
    for (int off = 32; off; off >>= 1) { a0 += __shfl_down(a0, off); a1 += __shfl_down(a1, off); }
    __shared__ float r0[4], r1[4];
    if (lane == 0) { r0[wv] = a0; r1[wv] = a1; }
    __syncthreads();
    if (t == 0) {
        const float s0 = r0[0] + r0[1] + r0[2] + r0[3];
        const float s1 = r1[0] + r1[1] + r1[2] + r1[3];
        const float m  = fmaxf(s0, s1);
        const float lse = m + __logf(__expf(s0 - m) + __expf(s1 - m));
        stp[b * 2] = s0 - lse;
        out[(size_t)b * 2049 + 2048] = s1 - lse;
    }
}

// ---------------- node logits: log_softmax over 2048 + stop0 ----------------
__global__ void node_k(const float* __restrict__ sc, const float* __restrict__ stp,
                       float* __restrict__ out) {
    const int b = blockIdx.x, t = threadIdx.x;
    const float* s = sc + (size_t)b * 2048;
    float v[8];
    float mx = -3.4e38f;
#pragma unroll
    for (int j = 0; j < 8; ++j) { v[j] = s[t + j * 256]; mx = fmaxf(mx, v[j]); }
    const int lane = t & 63, wv = t >> 6;
    __shared__ float red[4];
#pragma unroll
    for (int off = 32; off; off >>= 1) mx = fmaxf(mx, __shfl_down(mx, off));
    if (lane == 0) red[wv] = mx;
    __syncthreads();
    mx = fmaxf(fmaxf(red[0], red[1]), fmaxf(red[2], red[3]));
    float se = 0.f;
#pragma unroll
    for (int j = 0; j < 8; ++j) se += __expf(v[j] - mx);
    __syncthreads();
#pragma unroll
    for (int off = 32; off; off >>= 1) se += __shfl_down(se, off);
    if (lane == 0) red[wv] = se;
    __syncthreads();
    se = red[0] + red[1] + red[2] + red[3];
    const float base = stp[b * 2] - mx - __logf(se);
#pragma unroll
    for (int j = 0; j < 8; ++j) out[(size_t)b * 2049 + t + j * 256] = v[j] + base;
}

extern "C" void kernel_launch(void* const* d_in, const int* in_sizes, int n_in,
                              void* d_out, int out_size, void* d_ws, size_t ws_size,
                              hipStream_t stream) {
    (void)in_sizes; (void)n_in; (void)out_size;
    const float* x_seeds = (const float*)d_in[0];
    const float* x_nodes = (const float*)d_in[1];
    const float* W_seed  = (const float*)d_in[2];
    const float* W_node  = (const float*)d_in[3];
    const float* W1      = (const float*)d_in[4];
    const float* b1      = (const float*)d_in[5];
    const float* W2      = (const float*)d_in[6];
    const float* b2      = (const float*)d_in[7];
    const float* w_ns    = (const float*)d_in[8];
    const float* W_stop  = (const float*)d_in[9];
    float* out = (float*)d_out;

    const int N = 131072, H = 1024, B = 64;

    {
        auto f1 = gemm256_k<1>; auto f2 = gemm256_k<2>;
        hipFuncSetAttribute((const void*)f1, hipFuncAttributeMaxDynamicSharedMemorySize, 131072);
        hipFuncSetAttribute((const void*)f2, hipFuncAttributeMaxDynamicSharedMemorySize, 131072);
    }

    char* ws = (char*)d_ws;
    size_t off = 0;
    auto alloc = [&](size_t bytes) {
        char* p = ws + off;
        off += (bytes + 255) & ~(size_t)255;
        return p;
    };
    // ---- persistent (small) buffers ----
    unsigned short* wcat = (unsigned short*)alloc((size_t)H * 256 * 2);
    unsigned short* W1b  = (unsigned short*)alloc((size_t)H * H * 2);
    unsigned short* W2b  = (unsigned short*)alloc((size_t)H * H * 2);
    float* scores = (float*)alloc((size_t)N * 4);
    float* pool   = (float*)alloc((size_t)B * H * 4);
    float* stp    = (float*)alloc((size_t)B * 2 * 4);

    // ---- chunk sizing (per-row: 512B xcat + 2048B h0 + 2048B h1) ----
    const size_t per_row = 256 * 2 + 1024 * 2 + 1024 * 2;   // 4608 B
    size_t avail = (ws_size > off + (1u << 20)) ? (ws_size - off - (1u << 20)) : 0;
    long long mc_ll = (long long)(avail / per_row) / 2048 * 2048;
    int Mc = (int)(mc_ll < 2048 ? 2048 : (mc_ll > 65536 ? 65536 : mc_ll));

    unsigned short* xcat_c = (unsigned short*)alloc((size_t)Mc * 256 * 2);
    unsigned short* h0_c   = (unsigned short*)alloc((size_t)Mc * H * 2);
    unsigned short* h1_c   = (unsigned short*)alloc((size_t)Mc * H * 2);

    hipMemsetAsync(pool, 0, (size_t)B * H * 4, stream);
    hipMemsetAsync(scores, 0, (size_t)N * 4, stream);   // accumulated via atomics

    // ---- weights: convert once ----
    pack_cat_k<<<(H * 32) / 256, 256, 0, stream>>>(W_seed, W_node, wcat, H * 32);
    cvt_k<<<(H * H / 8) / 256, 256, 0, stream>>>(W1, W1b, H * H / 8);
    cvt_k<<<(H * H / 8) / 256, 256, 0, stream>>>(W2, W2b, H * H / 8);

    // ---- chunked row pipeline ----
    for (int base = 0; base < N; base += Mc) {
        const int m = (N - base < Mc) ? (N - base) : Mc;   // multiple of 2048
        pack_cat_k<<<(m * 32) / 256, 256, 0, stream>>>(
            x_seeds + (size_t)base * 128, x_nodes + (size_t)base * 128, xcat_c, m * 32);
        // GEMM1 (K=256) on the 128^2 kernel
        const int grid128 = (m / 128) * (H / 128);
        gemm_bt_k<0><<<grid128, 256, 0, stream>>>(xcat_c, wcat, nullptr, h0_c, m, H, 256);
        // GEMM2/GEMM3 (K=1024) on the 256^2 quadrant-phase kernel
        const int grid256 = (m / 256) * (H / 256);
        gemm256_k<1><<<grid256, 512, 131072, stream>>>(h0_c, W1b, b1, h1_c,
                                                       nullptr, nullptr, nullptr, m, H, H);
        gemm256_k<2><<<grid256, 512, 131072, stream>>>(h1_c, W2b, b2, nullptr,
                                                       w_ns, scores + base,
                                                       pool + (size_t)(base / 2048) * H, m, H, H);
    }

    stop_k<<<B, 256, 0, stream>>>(pool, W_stop, stp, out);
    node_k<<<B, 256, 0, stream>>>(scores, stp, out);
}

// Round 15
// 1069.763 us; speedup vs baseline: 1.0224x; 1.0224x over previous
//
#include <hip/hip_runtime.h>

typedef float f32x4 __attribute__((ext_vector_type(4)));
typedef __bf16 bf16x8 __attribute__((ext_vector_type(8)));
typedef unsigned short u16x8 __attribute__((ext_vector_type(8)));

#define DEVINL static __device__ __forceinline__

DEVINL unsigned short f2bf(float f) {
    unsigned int u = __builtin_bit_cast(unsigned int, f);
    u += 0x7fffu + ((u >> 16) & 1u);   // RNE
    return (unsigned short)(u >> 16);
}
DEVINL float bf2f(unsigned short u) {
    unsigned int x = ((unsigned int)u) << 16;
    return __builtin_bit_cast(float, x);
}

// async global->LDS, 16B per lane. LDS dest is wave-uniform base + lane*16.
#define GLD16(gp, lp)                                                          \
    __builtin_amdgcn_global_load_lds(                                          \
        (const __attribute__((address_space(1))) void*)(gp),                   \
        (__attribute__((address_space(3))) void*)(lp), 16, 0, 0)

// ---------------- packing kernels ----------------
__global__ void pack_cat_k(const float* __restrict__ s0, const float* __restrict__ s1,
                           unsigned short* __restrict__ dst, int nchunks) {
    int e = blockIdx.x * 256 + threadIdx.x;   // one 8-elem chunk
    if (e >= nchunks) return;
    int row = e >> 5, ch = e & 31;
    const float* src = (ch < 16) ? (s0 + (size_t)row * 128 + ch * 8)
                                 : (s1 + (size_t)row * 128 + (ch - 16) * 8);
    float4 a = *(const float4*)src;
    float4 b = *(const float4*)(src + 4);
    u16x8 o;
    o[0] = f2bf(a.x); o[1] = f2bf(a.y); o[2] = f2bf(a.z); o[3] = f2bf(a.w);
    o[4] = f2bf(b.x); o[5] = f2bf(b.y); o[6] = f2bf(b.z); o[7] = f2bf(b.w);
    *(u16x8*)(dst + (size_t)e * 8) = o;
}

__global__ void cvt_k(const float* __restrict__ s, unsigned short* __restrict__ d, int nchunks) {
    int e = blockIdx.x * 256 + threadIdx.x;
    if (e >= nchunks) return;
    float4 a = *(const float4*)(s + (size_t)e * 8);
    float4 b = *(const float4*)(s + (size_t)e * 8 + 4);
    u16x8 o;
    o[0] = f2bf(a.x); o[1] = f2bf(a.y); o[2] = f2bf(a.z); o[3] = f2bf(a.w);
    o[4] = f2bf(b.x); o[5] = f2bf(b.y); o[6] = f2bf(b.z); o[7] = f2bf(b.w);
    *(u16x8*)(d + (size_t)e * 8) = o;
}

// ---------------- 128^2 GEMM (GEMM1 + proven EPI=2 fused GEMM3) ----------
// EPI 0: C = A@B^T ; EPI 1: C = swish(+bias) ; EPI 2: swish(+bias), no store,
// atomic row-score + segment-pool accumulation (verified round 8, 1013us).
template <int EPI>
__global__ void gemm_bt_k(const unsigned short* __restrict__ A,
                          const unsigned short* __restrict__ B,
                          const float* __restrict__ bias,
                          unsigned short* __restrict__ C,
                          const float* __restrict__ wns,
                          float* __restrict__ sc,
                          float* __restrict__ pl,
                          int M, int N, int K) {
    __shared__ unsigned short As[128 * 32];
    __shared__ unsigned short Bs[128 * 32];
    const int tid  = threadIdx.x;
    const int lane = tid & 63;
    const int wv   = tid >> 6;
    const int wr   = wv >> 1, wc = wv & 1;
    const int ntn  = N >> 7;

    const int nwg = gridDim.x;
    const int xcd = blockIdx.x & 7, blk = blockIdx.x >> 3;
    const int q = nwg >> 3, rr = nwg & 7;
    const int logical = (xcd < rr ? xcd * (q + 1) : rr * (q + 1) + (xcd - rr) * q) + blk;

    const int im   = logical / ntn, in = logical % ntn;
    const size_t rowA0 = (size_t)im * 128, rowB0 = (size_t)in * 128;

    const int e0 = tid, e1 = tid + 256;
    const int ra0 = e0 >> 2, ca0 = (e0 & 3) * 8;
    const int ra1 = e1 >> 2, ca1 = (e1 & 3) * 8;

    f32x4 acc[4][4] = {};
    const int frow = lane & 15;
    const int kb   = (lane >> 4) * 8;

    for (int k0 = 0; k0 < K; k0 += 32) {
        GLD16(A + (rowA0 + ra0) * K + k0 + ca0, (char*)As + e0 * 16);
        GLD16(A + (rowA0 + ra1) * K + k0 + ca1, (char*)As + e1 * 16);
        GLD16(B + (rowB0 + ra0) * K + k0 + ca0, (char*)Bs + e0 * 16);
        GLD16(B + (rowB0 + ra1) * K + k0 + ca1, (char*)Bs + e1 * 16);
        __syncthreads();

        bf16x8 af[4], bfr[4];
#pragma unroll
        for (int m = 0; m < 4; ++m)
            af[m] = *(const bf16x8*)&As[(wr * 64 + m * 16 + frow) * 32 + kb];
#pragma unroll
        for (int n = 0; n < 4; ++n)
            bfr[n] = *(const bf16x8*)&Bs[(wc * 64 + n * 16 + frow) * 32 + kb];
#pragma unroll
        for (int m = 0; m < 4; ++m)
#pragma unroll
            for (int n = 0; n < 4; ++n)
                acc[m][n] = __builtin_amdgcn_mfma_f32_16x16x32_bf16(af[m], bfr[n], acc[m][n], 0, 0, 0);
        __syncthreads();
    }

    // C/D layout: col = lane&15, row = (lane>>4)*4 + reg
    const int r4 = (lane >> 4) * 4;
    const int cc = lane & 15;

    if (EPI == 2) {
#pragma unroll
        for (int n = 0; n < 4; ++n) {
            const float bv = bias[(int)rowB0 + wc * 64 + n * 16 + cc];
#pragma unroll
            for (int m = 0; m < 4; ++m)
#pragma unroll
                for (int r = 0; r < 4; ++r) {
                    float v = acc[m][n][r] + bv;
                    acc[m][n][r] = v / (1.0f + __expf(-v));
                }
        }
        // node scores: per-(m,r) row partial over this wave's 64 cols
#pragma unroll
        for (int m = 0; m < 4; ++m)
#pragma unroll
            for (int r = 0; r < 4; ++r) {
                float s = 0.f;
#pragma unroll
                for (int n = 0; n < 4; ++n)
                    s += acc[m][n][r] * wns[(int)rowB0 + wc * 64 + n * 16 + cc];
#pragma unroll
                for (int o = 1; o < 16; o <<= 1) s += __shfl_xor(s, o);
                if (cc == 0)
                    atomicAdd(&sc[rowA0 + wr * 64 + m * 16 + r4 + r], s);
            }
        // pool: per-n column partial over this wave's 64 rows
        const int seg = (int)(rowA0 >> 11);
#pragma unroll
        for (int n = 0; n < 4; ++n) {
            float p = 0.f;
#pragma unroll
            for (int m = 0; m < 4; ++m)
#pragma unroll
                for (int r = 0; r < 4; ++r) p += acc[m][n][r];
            p += __shfl_xor(p, 16);
            p += __shfl_xor(p, 32);
            if ((lane >> 4) == 0)
                atomicAdd(&pl[seg * 1024 + (int)rowB0 + wc * 64 + n * 16 + cc],
                          p * (1.0f / 2048.0f));
        }
        return;
    }

#pragma unroll
    for (int n = 0; n < 4; ++n) {
        const int col = (int)rowB0 + wc * 64 + n * 16 + cc;
        const float bv = (EPI == 1) ? bias[col] : 0.0f;
#pragma unroll
        for (int m = 0; m < 4; ++m) {
            const size_t row = rowA0 + wr * 64 + m * 16 + r4;
#pragma unroll
            for (int r = 0; r < 4; ++r) {
                float v = acc[m][n][r] + bv;
                if (EPI == 1) v = v / (1.0f + __expf(-v));
                C[(row + r) * (size_t)N + col] = f2bf(v);
            }
        }
    }
}

// ---------------- 256^2 quadrant-phase GEMM v3 (under test, GEMM2 only) ----
// BM=BN=256, BK=64, 8 waves (2Mx4N), per-wave 128x64 out via quadrants.
// Single vmcnt(4) per K-tile at P4; stage->consume 4-6 phases; templated
// parity. Swizzle pair HW-verified (bank conflicts = 0 in r11).
DEVINL int swz16(int b) { return b ^ (((b >> 7) & 7) << 4); }

template <int W>
DEVINL void vmw() {
    if constexpr (W == 8) asm volatile("s_waitcnt vmcnt(8)" ::: "memory");
    else if constexpr (W == 4) asm volatile("s_waitcnt vmcnt(4)" ::: "memory");
    else if constexpr (W == 0) asm volatile("s_waitcnt vmcnt(0)" ::: "memory");
}

template <int P, int MH, int NH, int W, typename F>
DEVINL void qphase(char* smA, char* smB, f32x4 (&acc)[8][4],
                   int wr, int wc, int fr, int kg, F&& stg) {
    char* Ab = smA + P * 32768 + MH * 16384;
    char* Bb = smB + P * 32768 + NH * 16384;
    bf16x8 aF[4][2], bF[2][2];
#pragma unroll
    for (int m2 = 0; m2 < 4; ++m2)
#pragma unroll
        for (int kk = 0; kk < 2; ++kk)
            aF[m2][kk] = *(const bf16x8*)(Ab + swz16((wr * 64 + m2 * 16 + fr) * 128 + kk * 64 + kg));
#pragma unroll
    for (int n2 = 0; n2 < 2; ++n2)
#pragma unroll
        for (int kk = 0; kk < 2; ++kk)
            bF[n2][kk] = *(const bf16x8*)(Bb + swz16((wc * 32 + n2 * 16 + fr) * 128 + kk * 64 + kg));
    stg();
    vmw<W>();
    __builtin_amdgcn_s_barrier();
    __builtin_amdgcn_s_setprio(1);
#pragma unroll
    for (int kk = 0; kk < 2; ++kk)
#pragma unroll
        for (int m2 = 0; m2 < 4; ++m2)
#pragma unroll
            for (int n2 = 0; n2 < 2; ++n2)
                acc[MH * 4 + m2][NH * 2 + n2] = __builtin_amdgcn_mfma_f32_16x16x32_bf16(
                    aF[m2][kk], bF[n2][kk], acc[MH * 4 + m2][NH * 2 + n2], 0, 0, 0);
    __builtin_amdgcn_s_setprio(0);
    __builtin_amdgcn_s_barrier();
}

__launch_bounds__(512, 1)
__global__ void gemm256_k(const unsigned short* __restrict__ A,
                          const unsigned short* __restrict__ Bm,
                          const float* __restrict__ bias,
                          unsigned short* __restrict__ C,
                          int M, int N, int K) {
    extern __shared__ __align__(16) char sm[];
    char* smA = sm;            // [parity][half][16384]
    char* smB = sm + 65536;
    const int tid  = threadIdx.x;
    const int lane = tid & 63, w = tid >> 6;
    const int wr = w >> 2, wc = w & 3;       // 2 x 4 waves
    const int fr = lane & 15;
    const int kg = (lane >> 4) * 16;         // 16B k-group within 64B window
    const int ntn = N >> 8;

    const int nwg = gridDim.x;
    const int xcd = blockIdx.x & 7, blk = blockIdx.x >> 3;
    const int q = nwg >> 3, rr = nwg & 7;
    const int logical = (xcd < rr ? xcd * (q + 1) : rr * (q + 1) + (xcd - rr) * q) + blk;
    const int im = logical / ntn, in = logical % ntn;
    const size_t rowA0 = (size_t)im * 256, colB0 = (size_t)in * 256;
    const int NT = K >> 6;                   // 64-wide K-tiles (even, >=4)

    f32x4 acc[8][4] = {};

    auto stageA = [&](int tile, int half, int par) {
#pragma unroll
        for (int j = 0; j < 2; ++j) {
            const int c = tid + j * 512;
            const int gc = (c & 7) ^ ((c >> 3) & 7);
            GLD16(A + (rowA0 + half * 128 + (c >> 3)) * K + tile * 64 + gc * 8,
                  smA + par * 32768 + half * 16384 + c * 16);
        }
    };
    auto stageB = [&](int tile, int half, int par) {
#pragma unroll
        for (int j = 0; j < 2; ++j) {
            const int c = tid + j * 512;
            const int gc = (c & 7) ^ ((c >> 3) & 7);
            GLD16(Bm + (colB0 + half * 128 + (c >> 3)) * K + tile * 64 + gc * 8,
                  smB + par * 32768 + half * 16384 + c * 16);
        }
    };
    auto nop = [] {};

    // prologue: tile0 all halves + tile1 A0,B0 (6 half-tiles, 12 loads);
    // vmcnt(4) covers tile0 fully, leaves tile1 A0,B0 in flight.
    stageA(0, 0, 0); stageB(0, 0, 0);
    stageB(0, 1, 0); stageA(0, 1, 0);
    stageA(1, 0, 1); stageB(1, 0, 1);
    vmw<4>();
    __builtin_amdgcn_s_barrier();

#define GRP_STEADY(Pp, tt)                                                           \
    qphase<Pp, 0, 0, -1>(smA, smB, acc, wr, wc, fr, kg, [&] { stageA(tt + 1, 1, Pp ^ 1); }); \
    qphase<Pp, 0, 1, -1>(smA, smB, acc, wr, wc, fr, kg, [&] { stageB(tt + 1, 1, Pp ^ 1); }); \
    qphase<Pp, 1, 0, -1>(smA, smB, acc, wr, wc, fr, kg, [&] { stageA(tt + 2, 0, Pp); });     \
    qphase<Pp, 1, 1,  4>(smA, smB, acc, wr, wc, fr, kg, [&] { stageB(tt + 2, 0, Pp); });

    for (int t = 0; t + 3 < NT; t += 2) {
        GRP_STEADY(0, t);
        GRP_STEADY(1, t + 1);
    }
#undef GRP_STEADY
    {   // group NT-2 (parity 0): stage only tile NT-1 halves A1,B1; drain.
        const int t = NT - 2;
        qphase<0, 0, 0, -1>(smA, smB, acc, wr, wc, fr, kg, [&] { stageA(t + 1, 1, 1); });
        qphase<0, 0, 1, -1>(smA, smB, acc, wr, wc, fr, kg, [&] { stageB(t + 1, 1, 1); });
        qphase<0, 1, 0, -1>(smA, smB, acc, wr, wc, fr, kg, nop);
        qphase<0, 1, 1,  0>(smA, smB, acc, wr, wc, fr, kg, nop);
    }
    {   // group NT-1 (parity 1): all landed, wait-free.
        qphase<1, 0, 0, -1>(smA, smB, acc, wr, wc, fr, kg, nop);
        qphase<1, 0, 1, -1>(smA, smB, acc, wr, wc, fr, kg, nop);
        qphase<1, 1, 0, -1>(smA, smB, acc, wr, wc, fr, kg, nop);
        qphase<1, 1, 1, -1>(smA, smB, acc, wr, wc, fr, kg, nop);
    }

    // epilogue (EPI=1 only: swish+bias, bf16 store).
    // row(m)=(m>>2)*128+wr*64+(m&3)*16+r4+r ; col(n)=(n>>1)*128+wc*32+(n&1)*16+cc
    const int r4 = (lane >> 4) * 4;
    const int cc = lane & 15;
#pragma unroll
    for (int n = 0; n < 4; ++n) {
        const int col = (int)colB0 + (n >> 1) * 128 + wc * 32 + (n & 1) * 16 + cc;
        const float bv = bias[col];
#pragma unroll
        for (int m = 0; m < 8; ++m) {
            const size_t row = rowA0 + (m >> 2) * 128 + wr * 64 + (m & 3) * 16 + r4;
#pragma unroll
            for (int r = 0; r < 4; ++r) {
                float v = acc[m][n][r] + bv;
                v = v / (1.0f + __expf(-v));   // swish
                C[(row + r) * (size_t)N + col] = f2bf(v);
            }
        }
    }
}

// ---------------- stop head: log_softmax(pool @ W_stop^T) ----------------
__global__ void stop_k(const float* __restrict__ pool, const float* __restrict__ Wstop,
                       float* __restrict__ stp, float* __restrict__ out) {
    const int b = blockIdx.x, t = threadIdx.x;
    float a0 = 0.f, a1 = 0.f;
#pragma unroll
    for (int j = 0; j < 4; ++j) {
        const int hcol = t + j * 256;
        const float pv = pool[b * 1024 + hcol];
        a0 += pv * Wstop[hcol];
        a1 += pv * Wstop[1024 + hcol];
    }
    const int lane = t & 63, wv = t >> 6;
#pragma unroll
    for (int off = 32; off; off >>= 1) { a0 += __shfl_down(a0, off); a1 += __shfl_down(a1, off); }
    __shared__ float r0[4], r1[4];
    if (lane == 0) { r0[wv] = a0; r1[wv] = a1; }
    __syncthreads();
    if (t == 0) {
        const float s0 = r0[0] + r0[1] + r0[2] + r0[3];
        const float s1 = r1[0] + r1[1] + r1[2] + r1[3];
        const float m  = fmaxf(s0, s1);
        const float lse = m + __logf(__expf(s0 - m) + __expf(s1 - m));
        stp[b * 2] = s0 - lse;
        out[(size_t)b * 2049 + 2048] = s1 - lse;
    }
}

// ---------------- node logits: log_softmax over 2048 + stop0 ----------------
__global__ void node_k(const float* __restrict__ sc, const float* __restrict__ stp,
                       float* __restrict__ out) {
    const int b = blockIdx.x, t = threadIdx.x;
    const float* s = sc + (size_t)b * 2048;
    float v[8];
    float mx = -3.4e38f;
#pragma unroll
    for (int j = 0; j < 8; ++j) { v[j] = s[t + j * 256]; mx = fmaxf(mx, v[j]); }
    const int lane = t & 63, wv = t >> 6;
    __shared__ float red[4];
#pragma unroll
    for (int off = 32; off; off >>= 1) mx = fmaxf(mx, __shfl_down(mx, off));
    if (lane == 0) red[wv] = mx;
    __syncthreads();
    mx = fmaxf(fmaxf(red[0], red[1]), fmaxf(red[2], red[3]));
    float se = 0.f;
#pragma unroll
    for (int j = 0; j < 8; ++j) se += __expf(v[j] - mx);
    __syncthreads();
#pragma unroll
    for (int off = 32; off; off >>= 1) se += __shfl_down(se, off);
    if (lane == 0) red[wv] = se;
    __syncthreads();
    se = red[0] + red[1] + red[2] + red[3];
    const float base = stp[b * 2] - mx - __logf(se);
#pragma unroll
    for (int j = 0; j < 8; ++j) out[(size_t)b * 2049 + t + j * 256] = v[j] + base;
}

extern "C" void kernel_launch(void* const* d_in, const int* in_sizes, int n_in,
                              void* d_out, int out_size, void* d_ws, size_t ws_size,
                              hipStream_t stream) {
    (void)in_sizes; (void)n_in; (void)out_size;
    const float* x_seeds = (const float*)d_in[0];
    const float* x_nodes = (const float*)d_in[1];
    const float* W_seed  = (const float*)d_in[2];
    const float* W_node  = (const float*)d_in[3];
    const float* W1      = (const float*)d_in[4];
    const float* b1      = (const float*)d_in[5];
    const float* W2      = (const float*)d_in[6];
    const float* b2      = (const float*)d_in[7];
    const float* w_ns    = (const float*)d_in[8];
    const float* W_stop  = (const float*)d_in[9];
    float* out = (float*)d_out;

    const int N = 131072, H = 1024, B = 64;

    hipFuncSetAttribute((const void*)&gemm256_k,
                        hipFuncAttributeMaxDynamicSharedMemorySize, 131072);

    char* ws = (char*)d_ws;
    size_t off = 0;
    auto alloc = [&](size_t bytes) {
        char* p = ws + off;
        off += (bytes + 255) & ~(size_t)255;
        return p;
    };
    // ---- persistent (small) buffers ----
    unsigned short* wcat = (unsigned short*)alloc((size_t)H * 256 * 2);
    unsigned short* W1b  = (unsigned short*)alloc((size_t)H * H * 2);
    unsigned short* W2b  = (unsigned short*)alloc((size_t)H * H * 2);
    float* scores = (float*)alloc((size_t)N * 4);
    float* pool   = (float*)alloc((size_t)B * H * 4);
    float* stp    = (float*)alloc((size_t)B * 2 * 4);

    // ---- chunk sizing (per-row: 512B xcat + 2048B h0 + 2048B h1) ----
    const size_t per_row = 256 * 2 + 1024 * 2 + 1024 * 2;   // 4608 B
    size_t avail = (ws_size > off + (1u << 20)) ? (ws_size - off - (1u << 20)) : 0;
    long long mc_ll = (long long)(avail / per_row) / 2048 * 2048;
    int Mc = (int)(mc_ll < 2048 ? 2048 : (mc_ll > 65536 ? 65536 : mc_ll));

    unsigned short* xcat_c = (unsigned short*)alloc((size_t)Mc * 256 * 2);
    unsigned short* h0_c   = (unsigned short*)alloc((size_t)Mc * H * 2);
    unsigned short* h1_c   = (unsigned short*)alloc((size_t)Mc * H * 2);

    hipMemsetAsync(pool, 0, (size_t)B * H * 4, stream);
    hipMemsetAsync(scores, 0, (size_t)N * 4, stream);   // accumulated via atomics

    // ---- weights: convert once ----
    pack_cat_k<<<(H * 32) / 256, 256, 0, stream>>>(W_seed, W_node, wcat, H * 32);
    cvt_k<<<(H * H / 8) / 256, 256, 0, stream>>>(W1, W1b, H * H / 8);
    cvt_k<<<(H * H / 8) / 256, 256, 0, stream>>>(W2, W2b, H * H / 8);

    // ---- chunked row pipeline ----
    for (int base = 0; base < N; base += Mc) {
        const int m = (N - base < Mc) ? (N - base) : Mc;   // multiple of 2048
        pack_cat_k<<<(m * 32) / 256, 256, 0, stream>>>(
            x_seeds + (size_t)base * 128, x_nodes + (size_t)base * 128, xcat_c, m * 32);
        const int grid128 = (m / 128) * (H / 128);
        // GEMM1 (K=256): proven 128^2
        gemm_bt_k<0><<<grid128, 256, 0, stream>>>(xcat_c, wcat, nullptr, h0_c,
                                                  nullptr, nullptr, nullptr, m, H, 256);
        // GEMM2 (K=1024): v3 256^2 under test  [A/B arm 1]
        const int grid256 = (m / 256) * (H / 256);
        gemm256_k<<<grid256, 512, 131072, stream>>>(h0_c, W1b, b1, h1_c, m, H, H);
        // GEMM3 (K=1024): proven 128^2 EPI=2 fused  [A/B arm 2]
        gemm_bt_k<2><<<grid128, 256, 0, stream>>>(h1_c, W2b, b2, nullptr,
                                                  w_ns, scores + base,
                                                  pool + (size_t)(base / 2048) * H, m, H, H);
    }

    stop_k<<<B, 256, 0, stream>>>(pool, W_stop, stp, out);
    node_k<<<B, 256, 0, stream>>>(scores, stp, out);
}